// Round 12
// baseline (30.933 us; speedup 1.0000x reference)
//
#include <hip/hip_runtime.h>

#define NN 256
#define NITER 20
static constexpr float KK = 14.426950408889634f; // (1/tau)*log2(e), tau=0.1

typedef float v2f __attribute__((ext_vector_type(2)));

template<int CTRL, int RM>
__device__ __forceinline__ float dppadd(float x) {
  int v = __builtin_amdgcn_update_dpp(0, __float_as_int(x), CTRL, RM, 0xF, true);
  return x + __int_as_float(v);
}
template<int CTRL, int RM>
__device__ __forceinline__ int dppaddi(int x) {
  int v = __builtin_amdgcn_update_dpp(0, x, CTRL, RM, 0xF, true);
  return x + v;
}
__device__ __forceinline__ float rlane(float v, int l) {
  return __int_as_float(__builtin_amdgcn_readlane(__float_as_int(v), l));
}
__device__ __forceinline__ float rcpf(float x) {
  float r; asm("v_rcp_f32 %0, %1" : "=v"(r) : "v"(x)); return r;
}
__device__ __forceinline__ int swz(int s) { return s + (s >> 4); }
// inclusive wave prefix over lane totals
__device__ __forceinline__ float wscanP(float t) {
  float s = t;
  s = dppadd<0x111,0xF>(s); s = dppadd<0x112,0xF>(s);
  s = dppadd<0x114,0xF>(s); s = dppadd<0x118,0xF>(s);
  s = dppadd<0x142,0xA>(s); s = dppadd<0x143,0xC>(s);
  return s;
}
// within-row inclusive suffix (row_shl); cross-row handled by readlanes outside
__device__ __forceinline__ float wscanS(float t) {
  float s = t;
  s = dppadd<0x101,0xF>(s); s = dppadd<0x102,0xF>(s);
  s = dppadd<0x104,0xF>(s); s = dppadd<0x108,0xF>(s);
  return s;
}

__global__ __launch_bounds__(64)
void sinkhorn_pk(const float* __restrict__ x,
                 const float* __restrict__ xn,
                 const float* __restrict__ refv,
                 float* __restrict__ out)
{
  // One wave, TWO batches packed in float2 register halves (pk-f32 math).
  // Single-wave workgroup: no __syncthreads; per-wave in-order DS ordering.
  __shared__ __align__(16) float4   W4[273];      // slot s at W4[swz(s)] = (P_A,P_B,Q_A,Q_B)
  __shared__ __align__(16) unsigned hist[2][NN];  // setup only
  __shared__ __align__(16) int      excl[2][NN];
  __shared__ __align__(16) float    xsS[2][NN];
  __shared__ __align__(16) int      ogS[2][NN];

  const int lane = threadIdx.x;   // 0..63
  const int j4 = lane * 4;
  const int row = lane >> 4;
  const int wbase = swz(j4);
  const size_t base0 = (size_t)(2 * blockIdx.x) * NN;

  float rv[4];
  { float4 t = *(const float4*)(refv + j4); rv[0]=t.x; rv[1]=t.y; rv[2]=t.z; rv[3]=t.w; }
  float Ep[4], Em[4];
  #pragma unroll
  for (int t = 0; t < 4; ++t) { Ep[t] = exp2f(KK*rv[t]); Em[t] = exp2f(-KK*rv[t]); }

  float xvS[2][4], EpxS[2][4], EmxS[2][4];
  int sJ[2][4], sM[2][4], orig_[2][4];

  // ---- setup per batch (R5-validated), p statically unrolled ----
  #pragma unroll
  for (int p = 0; p < 2; ++p) {
    const size_t bb = base0 + (size_t)p * NN;
    float xnv[4];
    { float4 t = *(const float4*)(xn + bb + j4); xnv[0]=t.x; xnv[1]=t.y; xnv[2]=t.z; xnv[3]=t.w; }
    { float4 t = *(const float4*)(x  + bb + j4); xvS[p][0]=t.x; xvS[p][1]=t.y; xvS[p][2]=t.z; xvS[p][3]=t.w; }
    *(uint4*)&hist[p][j4] = make_uint4(0u,0u,0u,0u);
    float vc[4]; int cb[4]; unsigned rtn[4];
    #pragma unroll
    for (int t = 0; t < 4; ++t) {
      vc[t] = fminf(fmaxf(xnv[t], -1.0f), 1.0f);   // clamp = exact row-shift invariance
      cb[t] = (int)fmaf(vc[t], 127.5f, 127.5f);    // bucket in [0,255]
      rtn[t] = atomicAdd(&hist[p][cb[t]], 1u);     // intra-bucket position
    }
    uint4 hv = *(uint4*)&hist[p][j4];               // in-order DS: after atomics
    int ih0=(int)hv.x, ih1=ih0+(int)hv.y, ih2=ih1+(int)hv.z, ih3=ih2+(int)hv.w;
    int sH = ih3;
    sH = dppaddi<0x111,0xF>(sH); sH = dppaddi<0x112,0xF>(sH);
    sH = dppaddi<0x114,0xF>(sH); sH = dppaddi<0x118,0xF>(sH);
    sH = dppaddi<0x142,0xA>(sH); sH = dppaddi<0x143,0xC>(sH);
    const int offH = sH - ih3;
    int b0=offH, b1=offH+ih0, b2=offH+ih1, b3=offH+ih2;
    *(int4*)&excl[p][j4] = make_int4(b0, b1, b2, b3);
    #pragma unroll
    for (int t = 0; t < 4; ++t) {
      int slot = excl[p][cb[t]] + (int)rtn[t];
      xsS[p][slot] = vc[t];
      ogS[p][slot] = j4 + t;
    }
    float xs_[4];
    { float4 t = *(float4*)&xsS[p][j4]; xs_[0]=t.x; xs_[1]=t.y; xs_[2]=t.z; xs_[3]=t.w; }
    { int4 t = *(int4*)&ogS[p][j4]; orig_[p][0]=t.x; orig_[p][1]=t.y; orig_[p][2]=t.z; orig_[p][3]=t.w; }
    sM[p][0]=swz(b0); sM[p][1]=swz(b1); sM[p][2]=swz(b2); sM[p][3]=swz(b3);
    #pragma unroll
    for (int t = 0; t < 4; ++t) {
      sJ[p][t] = swz((int)fmaf(xs_[t], 127.5f, 127.5f) + 1);
      EpxS[p][t] = exp2f( KK * xs_[t]);
      EmxS[p][t] = exp2f(-KK * xs_[t]);
    }
  }

  // packed per-slot constants
  v2f EPX[4], EMX[4], XV[4], vCp[4], vRp[4];
  #pragma unroll
  for (int t = 0; t < 4; ++t) {
    EPX[t] = (v2f){EpxS[0][t], EpxS[1][t]};
    EMX[t] = (v2f){EmxS[0][t], EmxS[1][t]};
    XV[t]  = (v2f){xvS[0][t],  xvS[1][t]};
    vCp[t] = (v2f){1.f, 1.f};
  }
  const float mk1 = (row < 1) ? 1.f : 0.f;   // lane-constant suffix masks
  const float mk2 = (row < 2) ? 1.f : 0.f;
  const float mk3 = (row < 3) ? 1.f : 0.f;

  // packed scan + publish: one instruction stream serves both batches
  auto scan_store = [&](v2f pa0, v2f pa1, v2f pa2, v2f pa3,
                        v2f qb0, v2f qb1, v2f qb2, v2f qb3) {
    v2f ip0=pa0, ip1=ip0+pa1, ip2=ip1+pa2, ip3=ip2+pa3;     // pk adds
    v2f sq3=qb3, sq2=sq3+qb2, sq1=sq2+qb1, sq0=sq1+qb0;     // pk adds
    float sPA = wscanP(ip3.x), sPB = wscanP(ip3.y);         // scalar DPP scans
    v2f offP; offP.x = sPA - ip3.x; offP.y = sPB - ip3.y;
    float sQA = wscanS(sq0.x), sQB = wscanS(sq0.y);
    float oQA = sQA - sq0.x, oQB = sQB - sq0.y;
    oQA = fmaf(mk1, rlane(sQA,16), oQA);
    oQA = fmaf(mk2, rlane(sQA,32), oQA);
    oQA = fmaf(mk3, rlane(sQA,48), oQA);
    oQB = fmaf(mk1, rlane(sQB,16), oQB);
    oQB = fmaf(mk2, rlane(sQB,32), oQB);
    oQB = fmaf(mk3, rlane(sQB,48), oQB);
    v2f offQ; offQ.x = oQA; offQ.y = oQB;
    v2f P1v = offP + ip0, P2v = offP + ip1, P3v = offP + ip2;            // pk
    v2f Q0v = offQ + sq0, Q1v = offQ + sq1, Q2v = offQ + sq2, Q3v = offQ + sq3; // pk
    W4[wbase+0] = make_float4(offP.x, offP.y, Q0v.x, Q0v.y);
    W4[wbase+1] = make_float4(P1v.x,  P1v.y,  Q1v.x, Q1v.y);
    W4[wbase+2] = make_float4(P2v.x,  P2v.y,  Q2v.x, Q2v.y);
    W4[wbase+3] = make_float4(P3v.x,  P3v.y,  Q3v.x, Q3v.y);
    if (lane == 63) W4[272] = make_float4(sPA, sPB, 0.f, 0.f);  // swz(256)
  };

  #pragma unroll 1
  for (int it = 0; it < NITER; ++it) {
    // row pass: vR = 1/(Emx*P_excl[sJ] + Epx*Q_incl[sJ]) per batch
    scan_store(Ep[0]*vCp[0], Ep[1]*vCp[1], Ep[2]*vCp[2], Ep[3]*vCp[3],
               Em[0]*vCp[0], Em[1]*vCp[1], Em[2]*vCp[2], Em[3]*vCp[3]);
    #pragma unroll
    for (int t = 0; t < 4; ++t) {
      const float* wa = (const float*)&W4[sJ[0][t]];   // -> ds_read2_b32 (0,2)
      const float* wb = (const float*)&W4[sJ[1][t]];   // -> ds_read2_b32 (1,3)
      float vA = rcpf(fmaf(EMX[t].x, wa[0], EPX[t].x * wa[2]));
      float vB = rcpf(fmaf(EMX[t].y, wb[1], EPX[t].y * wb[3]));
      vRp[t].x = vA; vRp[t].y = vB;
    }
    // col pass: vC = 1/(Em*P_excl[sM] + Ep*Q_incl[sM]) per batch
    scan_store(EPX[0]*vRp[0], EPX[1]*vRp[1], EPX[2]*vRp[2], EPX[3]*vRp[3],
               EMX[0]*vRp[0], EMX[1]*vRp[1], EMX[2]*vRp[2], EMX[3]*vRp[3]);
    #pragma unroll
    for (int t = 0; t < 4; ++t) {
      const float* wa = (const float*)&W4[sM[0][t]];
      const float* wb = (const float*)&W4[sM[1][t]];
      float vA = rcpf(fmaf(Em[t], wa[0], Ep[t] * wa[2]));
      float vB = rcpf(fmaf(Em[t], wb[1], Ep[t] * wb[3]));
      vCp[t].x = vA; vCp[t].y = vB;
    }
  }

  // ---- final weighted row pass, both batches ----
  {
    v2f g[4];
    #pragma unroll
    for (int t = 0; t < 4; ++t) g[t] = vCp[t] * XV[t];
    scan_store(Ep[0]*g[0], Ep[1]*g[1], Ep[2]*g[2], Ep[3]*g[3],
               Em[0]*g[0], Em[1]*g[1], Em[2]*g[2], Em[3]*g[3]);
    #pragma unroll
    for (int t = 0; t < 4; ++t) {
      const float* wa = (const float*)&W4[sJ[0][t]];
      const float* wb = (const float*)&W4[sJ[1][t]];
      float SA = fmaf(EMX[t].x, wa[0], EPX[t].x * wa[2]);
      float SB = fmaf(EMX[t].y, wb[1], EPX[t].y * wb[3]);
      xsS[0][orig_[0][t]] = vRp[t].x * SA;   // reuse as output staging
      xsS[1][orig_[1][t]] = vRp[t].y * SB;
    }
    float4 o0 = *(float4*)&xsS[0][j4];        // in-order DS: after writes
    float4 o1 = *(float4*)&xsS[1][j4];
    *(float4*)(out + base0 + j4)      = o0;
    *(float4*)(out + base0 + NN + j4) = o1;
  }
}

extern "C" void kernel_launch(void* const* d_in, const int* in_sizes, int n_in,
                              void* d_out, int out_size, void* d_ws, size_t ws_size,
                              hipStream_t stream) {
  const float* x    = (const float*)d_in[0];
  const float* xnrm = (const float*)d_in[1];
  const float* refv = (const float*)d_in[2];
  float* out = (float*)d_out;
  const int B = in_sizes[0] / NN;  // 2048 (even)
  sinkhorn_pk<<<dim3(B / 2), dim3(64), 0, stream>>>(x, xnrm, refv, out);
}

// Round 13
// 19.524 us; speedup vs baseline: 1.5843x; 1.5843x over previous
//
#include <hip/hip_runtime.h>

#define NN 256
#define NITER 20
static constexpr float KK = 14.426950408889634f; // (1/tau)*log2(e), tau=0.1

typedef float v2f __attribute__((ext_vector_type(2)));

template<int CTRL, int RM>
__device__ __forceinline__ float dppadd(float x) {
  int v = __builtin_amdgcn_update_dpp(0, __float_as_int(x), CTRL, RM, 0xF, true);
  return x + __int_as_float(v);
}
template<int CTRL, int RM>
__device__ __forceinline__ int dppaddi(int x) {
  int v = __builtin_amdgcn_update_dpp(0, x, CTRL, RM, 0xF, true);
  return x + v;
}
__device__ __forceinline__ float rlane(float v, int l) {
  return __int_as_float(__builtin_amdgcn_readlane(__float_as_int(v), l));
}
__device__ __forceinline__ float rcpf(float x) {
  float r; asm("v_rcp_f32 %0, %1" : "=v"(r) : "v"(x)); return r;
}
__device__ __forceinline__ int swz(int s) { return s + (s >> 4); }

__global__ __launch_bounds__(64)
void sinkhorn_wave(const float* __restrict__ x,
                   const float* __restrict__ xn,
                   const float* __restrict__ refv,
                   float* __restrict__ out)
{
  // Single-wave workgroup: no __syncthreads; per-wave in-order DS ordering.
  // Proven R5 structure (measured 20.6 us) + pk-f32 in-lane scan trees.
  __shared__ __align__(16) float2   W[274];     // swizzled; slot s at W[swz(s)]
  __shared__ __align__(16) unsigned hist[NN];
  __shared__ __align__(16) int      exclArr[NN];
  __shared__ __align__(16) float    xsArr[NN];
  __shared__ __align__(16) int      origArr[NN];

  const int lane = threadIdx.x;   // 0..63
  const int b = blockIdx.x;
  const int j4 = lane * 4;
  const size_t base = (size_t)b * NN;

  float xnv[4], xv[4], rv[4];
  { float4 t = *(const float4*)(xn + base + j4); xnv[0]=t.x; xnv[1]=t.y; xnv[2]=t.z; xnv[3]=t.w; }
  { float4 t = *(const float4*)(x  + base + j4); xv[0]=t.x;  xv[1]=t.y;  xv[2]=t.z;  xv[3]=t.w; }
  { float4 t = *(const float4*)(refv + j4);      rv[0]=t.x;  rv[1]=t.y;  rv[2]=t.z;  rv[3]=t.w; }

  // ---- bucket-group rows by grid cell ----
  *(uint4*)&hist[j4] = make_uint4(0u, 0u, 0u, 0u);
  float vc[4]; int cb[4]; unsigned rtn[4];
  #pragma unroll
  for (int t = 0; t < 4; ++t) {
    vc[t] = fminf(fmaxf(xnv[t], -1.0f), 1.0f);   // clamp = exact row-shift invariance
    cb[t] = (int)fmaf(vc[t], 127.5f, 127.5f);    // bucket in [0,255]
    rtn[t] = atomicAdd(&hist[cb[t]], 1u);        // intra-bucket position
  }
  uint4 hv = *(uint4*)&hist[j4];                  // in-order DS: after atomics
  int ih0 = (int)hv.x, ih1 = ih0 + (int)hv.y, ih2 = ih1 + (int)hv.z, ih3 = ih2 + (int)hv.w;
  int sH = ih3;
  sH = dppaddi<0x111,0xF>(sH); sH = dppaddi<0x112,0xF>(sH);
  sH = dppaddi<0x114,0xF>(sH); sH = dppaddi<0x118,0xF>(sH);
  sH = dppaddi<0x142,0xA>(sH); sH = dppaddi<0x143,0xC>(sH);
  const int offH = sH - ih3;
  int slotM[4] = { offH, offH + ih0, offH + ih1, offH + ih2 };
  *(int4*)&exclArr[j4] = make_int4(slotM[0], slotM[1], slotM[2], slotM[3]);
  #pragma unroll
  for (int t = 0; t < 4; ++t) {
    int slot = exclArr[cb[t]] + (int)rtn[t];
    xsArr[slot]   = vc[t];
    origArr[slot] = j4 + t;
  }
  float xs[4]; int orig[4];
  { float4 t = *(float4*)&xsArr[j4]; xs[0]=t.x; xs[1]=t.y; xs[2]=t.z; xs[3]=t.w; }
  { int4  t = *(int4*)&origArr[j4]; orig[0]=t.x; orig[1]=t.y; orig[2]=t.z; orig[3]=t.w; }

  int slotJ[4];
  #pragma unroll
  for (int t = 0; t < 4; ++t) {
    slotJ[t] = swz((int)fmaf(xs[t], 127.5f, 127.5f) + 1);
    slotM[t] = swz(slotM[t]);
  }

  float Ep[4], Em[4], Epx[4], Emx[4];
  #pragma unroll
  for (int t = 0; t < 4; ++t) {
    Ep[t]  = exp2f( KK * rv[t]);  Em[t]  = exp2f(-KK * rv[t]);
    Epx[t] = exp2f( KK * xs[t]);  Emx[t] = exp2f(-KK * xs[t]);
  }
  // pk coefficient pairs: z[t] = (P-coeff[t], Q-coeff[3-t]) so one packed
  // prefix tree yields prefix(P) AND suffix(Q) with identical FP ordering.
  v2f E2r[4], E2c[4];
  #pragma unroll
  for (int t = 0; t < 4; ++t) {
    E2r[t] = (v2f){Ep[t],  Em[3 - t]};
    E2c[t] = (v2f){Epx[t], Emx[3 - t]};
  }

  const int wbase = swz(j4);
  // packed scan + publish: z_t = (pa_t, qb_{3-t})
  auto scan_store = [&](v2f z0, v2f z1, v2f z2, v2f z3) {
    v2f s1 = z0 + z1;            // (pa0+pa1,            qb3+qb2)
    v2f s2 = s1 + z2;            // (pa0+..+pa2,         qb3+..+qb1)
    v2f s3 = s2 + z3;            // (ta,                 tc=sq0)
    float sP = s3.x;             // wave prefix over lane totals
    sP = dppadd<0x111,0xF>(sP); sP = dppadd<0x112,0xF>(sP);
    sP = dppadd<0x114,0xF>(sP); sP = dppadd<0x118,0xF>(sP);
    sP = dppadd<0x142,0xA>(sP); sP = dppadd<0x143,0xC>(sP);
    float offP = sP - s3.x;
    float sQ = s3.y;             // within-row inclusive suffix of lane totals
    sQ = dppadd<0x101,0xF>(sQ); sQ = dppadd<0x102,0xF>(sQ);
    sQ = dppadd<0x104,0xF>(sQ); sQ = dppadd<0x108,0xF>(sQ);
    float q1 = rlane(sQ, 16), q2 = rlane(sQ, 32), q3 = rlane(sQ, 48);
    int row = lane >> 4;
    float offQ = sQ - s3.y;
    offQ += (row < 1) ? q1 : 0.f;
    offQ += (row < 2) ? q2 : 0.f;
    offQ += (row < 3) ? q3 : 0.f;
    // slots: P_excl = offP + {0, z0.x, s1.x, s2.x}; Q_incl = offQ + {s3.y, s2.y, s1.y, z0.y}
    float4 w0 = make_float4(offP,        offQ + s3.y, offP + z0.x, offQ + s2.y);
    float4 w1 = make_float4(offP + s1.x, offQ + s1.y, offP + s2.x, offQ + z0.y);
    *(float4*)&W[wbase]     = w0;
    *(float4*)&W[wbase + 2] = w1;
    if (lane == 63) W[272] = make_float2(sP, 0.f);   // swz(256)
  };

  float vC[4] = {1.f, 1.f, 1.f, 1.f}, vR[4];
  #pragma unroll 1
  for (int it = 0; it < NITER; ++it) {
    // row pass: vR[m] = 1 / (Emx*P_excl[slotJ] + Epx*Q_incl[slotJ])
    scan_store(E2r[0] * (v2f){vC[0], vC[3]},
               E2r[1] * (v2f){vC[1], vC[2]},
               E2r[2] * (v2f){vC[2], vC[1]},
               E2r[3] * (v2f){vC[3], vC[0]});
    #pragma unroll
    for (int t = 0; t < 4; ++t) {
      float2 w = W[slotJ[t]];
      vR[t] = rcpf(fmaf(Emx[t], w.x, Epx[t] * w.y));
    }
    // col pass: vC[j] = 1 / (Em*P_excl[slotM] + Ep*Q_incl[slotM])
    scan_store(E2c[0] * (v2f){vR[0], vR[3]},
               E2c[1] * (v2f){vR[1], vR[2]},
               E2c[2] * (v2f){vR[2], vR[1]},
               E2c[3] * (v2f){vR[3], vR[0]});
    #pragma unroll
    for (int t = 0; t < 4; ++t) {
      float2 w = W[slotM[t]];
      vC[t] = rcpf(fmaf(Em[t], w.x, Ep[t] * w.y));
    }
  }
  // ---- final weighted row pass: out[orig_m] = vR_m * sum_j 2^{-k|xs-ref|} vC_j x_j ----
  {
    float g0 = vC[0]*xv[0], g1 = vC[1]*xv[1], g2 = vC[2]*xv[2], g3 = vC[3]*xv[3];
    scan_store(E2r[0] * (v2f){g0, g3},
               E2r[1] * (v2f){g1, g2},
               E2r[2] * (v2f){g2, g1},
               E2r[3] * (v2f){g3, g0});
    #pragma unroll
    for (int t = 0; t < 4; ++t) {
      float2 w = W[slotJ[t]];
      float S = fmaf(Emx[t], w.x, Epx[t] * w.y);
      xsArr[orig[t]] = vR[t] * S;               // reuse as output staging
    }
    float4 o = *(float4*)&xsArr[j4];             // in-order DS: after writes
    *(float4*)(out + base + j4) = o;
  }
}

extern "C" void kernel_launch(void* const* d_in, const int* in_sizes, int n_in,
                              void* d_out, int out_size, void* d_ws, size_t ws_size,
                              hipStream_t stream) {
  const float* x    = (const float*)d_in[0];
  const float* xnrm = (const float*)d_in[1];
  const float* refv = (const float*)d_in[2];
  float* out = (float*)d_out;
  const int B = in_sizes[0] / NN;  // 2048
  sinkhorn_wave<<<dim3(B), dim3(64), 0, stream>>>(x, xnrm, refv, out);
}